// Round 7
// baseline (202.690 us; speedup 1.0000x reference)
//
#include <hip/hip_runtime.h>
#include <hip/hip_bf16.h>

#define DEV static __device__ __forceinline__

typedef short bf16x8 __attribute__((ext_vector_type(8)));
typedef float f32x4  __attribute__((ext_vector_type(4)));
typedef unsigned u32x4 __attribute__((ext_vector_type(4)));

union U4 { uint4 u; bf16x8 s; };

DEV float b2f(__hip_bfloat16 v) { return __bfloat162float(v); }
DEV float lrelu(float e) { return e > 0.f ? e : 0.2f * e; }

DEV unsigned short f2bu(float f) {
    __hip_bfloat16 b = __float2bfloat16(f);
    return *reinterpret_cast<unsigned short*>(&b);
}
DEV float bu2f(unsigned short u) { return __uint_as_float((unsigned)u << 16); }

DEV float loadF(const void* p, size_t i, int f32) {
    if (f32) return ((const float*)p)[i];
    return b2f(((const __hip_bfloat16*)p)[i]);
}

DEV uint4 pack8(const unsigned short* t) {
    uint4 v;
    v.x = (unsigned)t[0] | ((unsigned)t[1] << 16);
    v.y = (unsigned)t[2] | ((unsigned)t[3] << 16);
    v.z = (unsigned)t[4] | ((unsigned)t[5] << 16);
    v.w = (unsigned)t[6] | ((unsigned)t[7] << 16);
    return v;
}

DEV u32x4 pack8v(const unsigned short* t) {
    u32x4 v;
    v.x = (unsigned)t[0] | ((unsigned)t[1] << 16);
    v.y = (unsigned)t[2] | ((unsigned)t[3] << 16);
    v.z = (unsigned)t[4] | ((unsigned)t[5] << 16);
    v.w = (unsigned)t[6] | ((unsigned)t[7] << 16);
    return v;
}

DEV void edge_sd(int i, int E, const int* __restrict__ src, const int* __restrict__ dst,
                 int& s, int& d) {
    if (i < E) { s = src[i]; d = dst[i]; }
    else       { s = d = i - E; }  // self-loops appended as arange(N)
}

// detect helper: wave-level 256-sample scan of one array's low 16-bit halves
DEV int detect_wave(const void* p, int n, int lane) {
    const unsigned short* u16 = (const unsigned short*)p;
    bool insane = false;
#pragma unroll
    for (int r = 0; r < 4; ++r) {
        int idx = lane + r * 64;
        if (idx < n) {
            unsigned short u = u16[idx];
            unsigned e = (u >> 7) & 0xFFu;
            insane |= (e >= 0xC8u) || (e == 0u && (u & 0x7Fu) != 0u);
        }
    }
    return (__ballot(insane) != 0ull) ? 1 : 0;
}

#define G_BIN 128

// ---------------- K1: fused gemm1 (blocks [0,gb)) + binA hist ([gb,gb+G_BIN))
//                  + dtype detect (block gb+G_BIN) ----------------
__global__ __launch_bounds__(256) void k_fused1(
    const void* __restrict__ x, const void* __restrict__ W,
    const void* __restrict__ a_s, const void* __restrict__ a_d,
    __hip_bfloat16* __restrict__ h, float* __restrict__ als, float* __restrict__ ald,
    int N, int gb, int nx, int nW1,
    const int* __restrict__ src, const int* __restrict__ dst,
    int* __restrict__ hist, int E, int EA, int chunk,
    const void* a5, int n5, const void* a6, int n6, const void* a7, int n7,
    const void* a8, int n8, const void* a9, int n9,
    int* __restrict__ flags)
{
    const int tid = threadIdx.x;
    const int bid = blockIdx.x;

    if (bid >= gb) {
        if (bid == gb + G_BIN) {
            const void* ps[9] = {x, W, a_s, a_d, a5, a6, a7, a8, a9};
            const int   ns[9] = {nx, nW1, 64, 64, n5, n6, n7, n8, n9};
            const int w = tid >> 6, lane = tid & 63;
            for (int k = w; k < 9; k += 4) {
                int f = detect_wave(ps[k], ns[k], lane);
                if (lane == 0) flags[k] = f;
            }
            return;
        }
        // ---- binA: coarse histogram ----
        __shared__ int cnt[256];
        cnt[tid] = 0;
        __syncthreads();
        const int cb = bid - gb;
        const int lo = cb * chunk;
        const int hi = min(lo + chunk, EA);
        for (int i = lo + tid; i < hi; i += 256) {
            int s, d; edge_sd(i, E, src, dst, s, d);
            atomicAdd(&cnt[d >> 8], 1);
        }
        __syncthreads();
        hist[cb * 256 + tid] = cnt[tid];
        return;
    }

    // ---- gemm1: h = x(N,128)@W1(128,64) + fused logits ----
    __shared__ __align__(16) unsigned short sMem[2 * 64 * 136];
    __shared__ float sAs[64], sAd[64];
    __shared__ int sFl[4];
    unsigned short* sA = sMem;
    unsigned short* sB = sMem + 64 * 136;
    float* sOut = (float*)sMem;

    {
        const void* ps4[4] = {x, W, a_s, a_d};
        const int   ns4[4] = {nx, nW1, 64, 64};
        const int w = tid >> 6, lane = tid & 63;
        int f = detect_wave(ps4[w], ns4[w], lane);
        if (lane == 0) sFl[w] = f;
    }
    __syncthreads();
    const int fx = sFl[0], fw = sFl[1];

    const int row0 = bid * 64;
    if (tid < 64) sAs[tid] = loadF(a_s, tid, sFl[2]);
    else if (tid < 128) sAd[tid - 64] = loadF(a_d, tid - 64, sFl[3]);

    if (!fx) {
        const uint4* xg = (const uint4*)x;
#pragma unroll
        for (int it = 0; it < 2; ++it) {
            int g = tid + it * 256;
            int r = g >> 4, c16 = g & 15;
            uint4 v = (row0 + r < N) ? xg[(size_t)(row0 + r) * 16 + c16]
                                     : make_uint4(0, 0, 0, 0);
            *(uint4*)(sA + r * 136 + c16 * 8) = v;
        }
    } else {
        for (int i = tid; i < 64 * 128; i += 256) {
            int r = i >> 7, k = i & 127;
            float v = (row0 + r < N) ? ((const float*)x)[(size_t)(row0 + r) * 128 + k] : 0.f;
            sA[r * 136 + k] = f2bu(v);
        }
    }
    if (!fw) {
        const unsigned short* Wg = (const unsigned short*)W;
        const int n = tid & 63;
        int k0 = (tid >> 6) * 8;
#pragma unroll
        for (int rep = 0; rep < 4; ++rep, k0 += 32) {
            unsigned short t[8];
#pragma unroll
            for (int j = 0; j < 8; ++j) t[j] = Wg[(size_t)(k0 + j) * 64 + n];
            *(uint4*)(sB + n * 136 + k0) = pack8(t);
        }
    } else {
        const float* Wg = (const float*)W;
        for (int i = tid; i < 128 * 64; i += 256) {
            int k = i >> 6, n = i & 63;
            sB[n * 136 + k] = f2bu(Wg[i]);
        }
    }
    __syncthreads();

    const int w = tid >> 6, lane = tid & 63;
    const int m0 = w * 16;
    const int qr = lane >> 4;
    const int lc = lane & 15;

    bf16x8 afrag[4];
#pragma unroll
    for (int c = 0; c < 4; ++c) {
        U4 u; u.u = *(const uint4*)(sA + (m0 + lc) * 136 + c * 32 + qr * 8);
        afrag[c] = u.s;
    }
    f32x4 accs[4];
#pragma unroll
    for (int nt = 0; nt < 4; ++nt) {
        f32x4 acc = {0.f, 0.f, 0.f, 0.f};
#pragma unroll
        for (int c = 0; c < 4; ++c) {
            U4 u; u.u = *(const uint4*)(sB + (nt * 16 + lc) * 136 + c * 32 + qr * 8);
            acc = __builtin_amdgcn_mfma_f32_16x16x32_bf16(afrag[c], u.s, acc, 0, 0, 0);
        }
        accs[nt] = acc;
    }
    __syncthreads();

#pragma unroll
    for (int nt = 0; nt < 4; ++nt)
#pragma unroll
        for (int reg = 0; reg < 4; ++reg)
            sOut[(m0 + qr * 4 + reg) * 68 + nt * 16 + lc] = accs[nt][reg];
    __syncthreads();

    {
        const int r = tid >> 2, seg = tid & 3;
        const int row = row0 + r;
        const float* po = sOut + r * 68 + seg * 16;
        float ps = 0.f, pd = 0.f;
        unsigned short ob[16];
#pragma unroll
        for (int i = 0; i < 16; ++i) {
            float v = po[i];
            ps = fmaf(v, sAs[seg * 16 + i], ps);
            pd = fmaf(v, sAd[seg * 16 + i], pd);
            ob[i] = f2bu(v);
        }
        if (row < N) {
            uint4* hp = (uint4*)((unsigned short*)h + (size_t)row * 64 + seg * 16);
            hp[0] = pack8(ob);
            hp[1] = pack8(ob + 8);
        }
        ps += __shfl_xor(ps, 1, 64); ps += __shfl_xor(ps, 2, 64);
        pd += __shfl_xor(pd, 1, 64); pd += __shfl_xor(pd, 2, 64);
        if (seg == 0 && row < N) { als[row] = ps; ald[row] = pd; }
    }
}

// ---------------- binC2: fused scan + scatter ----------------
__global__ __launch_bounds__(256) void k_binC2(
    const int* __restrict__ src, const int* __restrict__ dst,
    const int* __restrict__ hist, int* __restrict__ btot,
    unsigned* __restrict__ ebuf, int E, int EA, int chunk)
{
    __shared__ int sm[256];
    __shared__ int cur[256];
    const int tid = threadIdx.x;
    const int cb = blockIdx.x;

    int tot = 0, mine = 0;
#pragma unroll 4
    for (int c = 0; c < G_BIN; ++c) {
        int v = hist[c * 256 + tid];     // coalesced across tid
        tot += v;
        if (c < cb) mine += v;
    }
    if (cb == 0) btot[tid] = tot;
    sm[tid] = tot;
    __syncthreads();
#pragma unroll
    for (int off = 1; off < 256; off <<= 1) {
        int t = (tid >= off) ? sm[tid - off] : 0;
        __syncthreads();
        sm[tid] += t;
        __syncthreads();
    }
    cur[tid] = (sm[tid] - tot) + mine;   // bucket start + my block's offset
    __syncthreads();
    const int lo = cb * chunk;
    const int hi = min(lo + chunk, EA);
    for (int i = lo + tid; i < hi; i += 256) {
        int s, d; edge_sd(i, E, src, dst, s, d);
        int pos = atomicAdd(&cur[d >> 8], 1);
        ebuf[pos] = ((unsigned)(d & 255) << 17) | (unsigned)s;
    }
}

// ---------------- binD: per-bucket node sort -> row_ptr + paired edge records ----------------
__global__ __launch_bounds__(256) void k_binD(
    const unsigned* __restrict__ ebuf, const int* __restrict__ btot,
    const float* __restrict__ als,
    int* __restrict__ row_ptr, int2* __restrict__ ecol, int N)
{
    __shared__ int sm[256];
    __shared__ int cnt[256];
    __shared__ int pfx[256];
    const int tid = threadIdx.x;
    const int b = blockIdx.x;
    {
        int v = btot[tid];
        sm[tid] = v;
        __syncthreads();
#pragma unroll
        for (int off = 1; off < 256; off <<= 1) {
            int t = (tid >= off) ? sm[tid - off] : 0;
            __syncthreads();
            sm[tid] += t;
            __syncthreads();
        }
    }
    const int lo = (b == 0) ? 0 : sm[b - 1];
    const int hi = sm[b];
    cnt[tid] = 0;
    __syncthreads();
    for (int i = lo + tid; i < hi; i += 256)
        atomicAdd(&cnt[ebuf[i] >> 17], 1);
    __syncthreads();
    const int c = cnt[tid];
    pfx[tid] = c;
    __syncthreads();
#pragma unroll
    for (int off = 1; off < 256; off <<= 1) {
        int t = (tid >= off) ? pfx[tid - off] : 0;
        __syncthreads();
        pfx[tid] += t;
        __syncthreads();
    }
    const int excl = pfx[tid] - c;
    const int d = b * 256 + tid;
    if (d <= N) row_ptr[d] = lo + excl;
    __syncthreads();
    cnt[tid] = lo + excl;              // reuse as absolute cursor
    __syncthreads();
    for (int i = lo + tid; i < hi; i += 256) {
        unsigned v = ebuf[i];
        const int s = (int)(v & 0x1FFFFu);
        int pos = atomicAdd(&cnt[v >> 17], 1);
        ecol[pos] = make_int2(s, __float_as_int(als[s]));
    }
}

// ---------------- gather1 + MFMA-fused layer-2 GEMM ----------------
// Phase 1: eg/fg CSR gather per wave (R5 structure, streaming ecol weights);
//          rel = relu(agg+b1) parked as bf16 rows in LDS (4 waves x npw slots).
// Phase 2: 32x64 @ 64x64 MFMA (gemm2's tile, W2 staged once per block);
//          als2/ald2 from f32 accumulators (gemm2-equivalent fidelity).
// Phase 3: h2 rows + logits stored. Kills the gemm2 dispatch, its launch gap,
//          and the aggbuf bf16 round-trip.
__global__ __launch_bounds__(256) void k_gat1g2(
    const int* __restrict__ row_ptr, const int2* __restrict__ ecol,
    const float* __restrict__ ald,
    const __hip_bfloat16* __restrict__ h,
    __hip_bfloat16* __restrict__ h2,
    float* __restrict__ als2, float* __restrict__ ald2,
    const void* __restrict__ b1, const void* __restrict__ W2,
    const void* __restrict__ a_s2, const void* __restrict__ a_d2,
    const int* __restrict__ flags, int N, int npw)
{
    __shared__ __align__(16) unsigned short sB[64 * 72];
    __shared__ __align__(16) unsigned short sRel[32 * 72];
    __shared__ float sB1[64], sAs2[64], sAd2[64];
    __shared__ float sPs[32], sPd[32];
    __shared__ int sNode[32];

    const int tid = threadIdx.x;

    // ---- staging: W2 (bf16 [n][k] stride 72), b1, a2 vectors; zero slots ----
    if (!flags[5]) {
        const unsigned short* Wg = (const unsigned short*)W2;
        const int n = tid & 63;
        int k0 = (tid >> 6) * 8;
#pragma unroll
        for (int rep = 0; rep < 2; ++rep, k0 += 32) {
            unsigned short t[8];
#pragma unroll
            for (int j = 0; j < 8; ++j) t[j] = Wg[(size_t)(k0 + j) * 64 + n];
            *(uint4*)(sB + n * 72 + k0) = pack8(t);
        }
    } else {
        const float* Wg = (const float*)W2;
        for (int i = tid; i < 64 * 64; i += 256) {
            int k = i >> 6, n = i & 63;
            sB[n * 72 + k] = f2bu(Wg[i]);
        }
    }
    if (tid < 64) sB1[tid] = loadF(b1, tid, flags[4]);
    else if (tid < 128) sAs2[tid - 64] = loadF(a_s2, tid - 64, flags[6]);
    else if (tid < 192) sAd2[tid - 128] = loadF(a_d2, tid - 128, flags[7]);
    if (tid < 32) { sNode[tid] = -1; sPs[tid] = 0.f; sPd[tid] = 0.f; }
    for (int i = tid; i < 32 * 72; i += 256) sRel[i] = 0;
    __syncthreads();

    const int lane = tid & 63, wave = tid >> 6;
    const int eg = lane >> 3, fg = lane & 7;
    const int wid = blockIdx.x * 4 + wave;
    const int nw  = gridDim.x * 4;

    // ---- phase 1: gather + rel rows into LDS ----
    for (int k = 0; k < npw; ++k) {
        const int d = wid + k * nw;
        if (d >= N) break;
        const int slot = wave * npw + k;
        if (lane == 0) sNode[slot] = d;
        const float aldd = ald[d];
        const int beg = row_ptr[d], end = row_ptr[d + 1];
        float acc[8] = {0.f,0.f,0.f,0.f,0.f,0.f,0.f,0.f};
        float den = 0.f;
        int j = beg + eg;
        if (j < end) {
            int2 e = ecol[j];
            float aC = __int_as_float(e.y);     // streaming weight (als1 embedded)
            uint4 hvC = *reinterpret_cast<const uint4*>(h + (size_t)e.x * 64 + fg * 8);
            for (; j < end; j += 8) {
                const int jn = j + 8;
                int2 eN = make_int2(0, 0);
                uint4 hvN = make_uint4(0, 0, 0, 0);
                if (jn < end) {                 // 1-ahead: record + h row
                    eN = ecol[jn];
                    hvN = *reinterpret_cast<const uint4*>(h + (size_t)eN.x * 64 + fg * 8);
                }
                const float w = __expf(lrelu(aC + aldd));
                den += w;
                acc[0] = fmaf(w, __uint_as_float(hvC.x << 16),          acc[0]);
                acc[1] = fmaf(w, __uint_as_float(hvC.x & 0xFFFF0000u),  acc[1]);
                acc[2] = fmaf(w, __uint_as_float(hvC.y << 16),          acc[2]);
                acc[3] = fmaf(w, __uint_as_float(hvC.y & 0xFFFF0000u),  acc[3]);
                acc[4] = fmaf(w, __uint_as_float(hvC.z << 16),          acc[4]);
                acc[5] = fmaf(w, __uint_as_float(hvC.z & 0xFFFF0000u),  acc[5]);
                acc[6] = fmaf(w, __uint_as_float(hvC.w << 16),          acc[6]);
                acc[7] = fmaf(w, __uint_as_float(hvC.w & 0xFFFF0000u),  acc[7]);
                aC = __int_as_float(eN.y); hvC = hvN;
            }
        }
#pragma unroll
        for (int off = 8; off <= 32; off <<= 1) {
            den += __shfl_xor(den, off, 64);
#pragma unroll
            for (int q = 0; q < 8; ++q) acc[q] += __shfl_xor(acc[q], off, 64);
        }
        if (eg == 0) {
            const float inv = 1.f / den;
            unsigned short ob[8];
#pragma unroll
            for (int q = 0; q < 8; ++q) {
                float v = fmaf(acc[q], inv, sB1[fg * 8 + q]);
                ob[q] = f2bu(v > 0.f ? v : 0.f);
            }
            *(uint4*)(sRel + slot * 72 + fg * 8) = pack8(ob);
        }
    }
    __syncthreads();

    // ---- phase 2: MFMA 32x64 @ W2, logits from f32 accs ----
    {
        const int qr = lane >> 4, lc = lane & 15;
        const int roww = wave & 1, colpair = wave >> 1;
        const int m0 = roww * 16;

        bf16x8 af[2];
#pragma unroll
        for (int c = 0; c < 2; ++c) {
            U4 u; u.u = *(const uint4*)(sRel + (m0 + lc) * 72 + c * 32 + qr * 8);
            af[c] = u.s;
        }
        __syncthreads();   // all fragment reads done before sRel is overwritten

        f32x4 accs[2];
#pragma unroll
        for (int t = 0; t < 2; ++t) {
            const int ct = colpair * 2 + t;
            f32x4 acc = {0.f, 0.f, 0.f, 0.f};
#pragma unroll
            for (int c = 0; c < 2; ++c) {
                U4 u; u.u = *(const uint4*)(sB + (ct * 16 + lc) * 72 + c * 32 + qr * 8);
                acc = __builtin_amdgcn_mfma_f32_16x16x32_bf16(af[c], u.s, acc, 0, 0, 0);
            }
            accs[t] = acc;
        }

        float psr[4] = {0.f,0.f,0.f,0.f}, pdr[4] = {0.f,0.f,0.f,0.f};
#pragma unroll
        for (int t = 0; t < 2; ++t) {
            const int col = (colpair * 2 + t) * 16 + lc;
            const float cs = sAs2[col], cd = sAd2[col];
#pragma unroll
            for (int reg = 0; reg < 4; ++reg) {
                psr[reg] = fmaf(accs[t][reg], cs, psr[reg]);
                pdr[reg] = fmaf(accs[t][reg], cd, pdr[reg]);
                sRel[(m0 + qr * 4 + reg) * 72 + col] = f2bu(accs[t][reg]);
            }
        }
#pragma unroll
        for (int off = 1; off <= 8; off <<= 1) {
#pragma unroll
            for (int reg = 0; reg < 4; ++reg) {
                psr[reg] += __shfl_xor(psr[reg], off, 64);
                pdr[reg] += __shfl_xor(pdr[reg], off, 64);
            }
        }
        if (lc == 0) {
#pragma unroll
            for (int reg = 0; reg < 4; ++reg) {
                atomicAdd(&sPs[m0 + qr * 4 + reg], psr[reg]);
                atomicAdd(&sPd[m0 + qr * 4 + reg], pdr[reg]);
            }
        }
    }
    __syncthreads();

    // ---- phase 3: h2 rows + logits out ----
    {
        const int r = tid >> 3, seg = tid & 7;
        const int d = sNode[r];
        if (d >= 0) {
            uint4 v = *(const uint4*)(sRel + r * 72 + seg * 8);
            *(uint4*)((unsigned short*)h2 + (size_t)d * 64 + seg * 8) = v;
            if (seg == 0) { als2[d] = sPs[r]; ald2[d] = sPd[r]; }
        }
    }
}

// ---------------- gather2: CSR gather + softmax + bias -> output ----------------
__global__ __launch_bounds__(256) void k_gather2(
    const int* __restrict__ row_ptr, const int2* __restrict__ ecol,
    const float* __restrict__ als, const float* __restrict__ ald,
    const __hip_bfloat16* __restrict__ h,
    void* __restrict__ final_out,
    const void* __restrict__ bias, const int* __restrict__ flags, int N)
{
    const int tid = threadIdx.x;
    const int lane = tid & 63;
    const int eg = lane >> 3, fg = lane & 7;
    const int wid = blockIdx.x * 4 + (tid >> 6);
    const int nw  = gridDim.x * 4;

    float bv[8];
    const int f0 = flags[0];
#pragma unroll
    for (int k = 0; k < 8; ++k) bv[k] = loadF(bias, fg * 8 + k, flags[8]);

    for (int d = wid; d < N; d += nw) {
        const float aldd = ald[d];
        const int beg = row_ptr[d], end = row_ptr[d + 1];
        float acc[8] = {0.f,0.f,0.f,0.f,0.f,0.f,0.f,0.f};
        float den = 0.f;
        int j = beg + eg;
        if (j < end) {
            int2 e = ecol[j];
            float aC = als[e.x];
            uint4 hvC = *reinterpret_cast<const uint4*>(h + (size_t)e.x * 64 + fg * 8);
            for (; j < end; j += 8) {
                const int jn = j + 8;
                int2 eN = make_int2(0, 0);
                float aN = 0.f;
                uint4 hvN = make_uint4(0, 0, 0, 0);
                if (jn < end) {
                    eN = ecol[jn];
                    aN = als[eN.x];
                    hvN = *reinterpret_cast<const uint4*>(h + (size_t)eN.x * 64 + fg * 8);
                }
                const float w = __expf(lrelu(aC + aldd));
                den += w;
                acc[0] = fmaf(w, __uint_as_float(hvC.x << 16),          acc[0]);
                acc[1] = fmaf(w, __uint_as_float(hvC.x & 0xFFFF0000u),  acc[1]);
                acc[2] = fmaf(w, __uint_as_float(hvC.y << 16),          acc[2]);
                acc[3] = fmaf(w, __uint_as_float(hvC.y & 0xFFFF0000u),  acc[3]);
                acc[4] = fmaf(w, __uint_as_float(hvC.z << 16),          acc[4]);
                acc[5] = fmaf(w, __uint_as_float(hvC.z & 0xFFFF0000u),  acc[5]);
                acc[6] = fmaf(w, __uint_as_float(hvC.w << 16),          acc[6]);
                acc[7] = fmaf(w, __uint_as_float(hvC.w & 0xFFFF0000u),  acc[7]);
                aC = aN; hvC = hvN;
            }
        }
#pragma unroll
        for (int off = 8; off <= 32; off <<= 1) {
            den += __shfl_xor(den, off, 64);
#pragma unroll
            for (int q = 0; q < 8; ++q) acc[q] += __shfl_xor(acc[q], off, 64);
        }
        if (eg == 0) {
            const float inv = 1.f / den;
            float vb[8];
#pragma unroll
            for (int q = 0; q < 8; ++q) vb[q] = fmaf(acc[q], inv, bv[q]);
            if (f0) {
                float* o = (float*)final_out + (size_t)d * 64 + fg * 8;
                f32x4 o0 = {vb[0], vb[1], vb[2], vb[3]};
                f32x4 o1 = {vb[4], vb[5], vb[6], vb[7]};
                __builtin_nontemporal_store(o0, (f32x4*)o);
                __builtin_nontemporal_store(o1, (f32x4*)(o + 4));
            } else {
                unsigned short ob[8];
#pragma unroll
                for (int q = 0; q < 8; ++q) ob[q] = f2bu(vb[q]);
                __builtin_nontemporal_store(pack8v(ob),
                    reinterpret_cast<u32x4*>((__hip_bfloat16*)final_out + (size_t)d * 64 + fg * 8));
            }
        }
    }
}

extern "C" void kernel_launch(void* const* d_in, const int* in_sizes, int n_in,
                              void* d_out, int out_size, void* d_ws, size_t ws_size,
                              hipStream_t stream)
{
    const void* x   = d_in[0];
    const int*  ei  = (const int*)d_in[1];
    const void* W1  = d_in[2];
    const void* as1 = d_in[3];
    const void* ad1 = d_in[4];
    const void* b1  = d_in[5];
    const void* W2  = d_in[6];
    const void* as2 = d_in[7];
    const void* ad2 = d_in[8];
    const void* b2  = d_in[9];

    const int N  = in_sizes[0] / 128;   // 50000
    const int E  = in_sizes[1] / 2;     // 800000
    const int EA = E + N;
    const int* src = ei;
    const int* dst = ei + E;

    uintptr_t base = (uintptr_t)d_ws;
    auto alloc = [&](size_t bytes) { uintptr_t p = base; base += (bytes + 63) & ~(size_t)63; return p; };
    int*      flags    = (int*)alloc(64 * 4);
    float*    als      = (float*)alloc((size_t)N * 4);
    float*    ald      = (float*)alloc((size_t)N * 4);
    float*    als2     = (float*)alloc((size_t)N * 4);
    float*    ald2     = (float*)alloc((size_t)N * 4);
    int*      row_ptr  = (int*)alloc((size_t)(N + 1) * 4);
    int*      hist     = (int*)alloc((size_t)G_BIN * 256 * 4);
    int*      btot     = (int*)alloc(256 * 4);
    unsigned* ebuf     = (unsigned*)alloc((size_t)EA * 4);
    int2*     ecol     = (int2*)alloc((size_t)EA * 8);
    __hip_bfloat16* hbuf   = (__hip_bfloat16*)alloc((size_t)N * 64 * 2);
    __hip_bfloat16* h2buf  = (__hip_bfloat16*)alloc((size_t)N * 64 * 2);

    const int gatherb = 2048;             // 8192 waves
    const int npw = (N + gatherb * 4 - 1) / (gatherb * 4);  // 7 -> 28 slots/block
    const int gb  = (N + 63) / 64;        // gemm blocks: 64 rows/block
    const int NBK = (N + 255) / 256;      // dst buckets (<= 256)
    const int chunk = (EA + G_BIN - 1) / G_BIN;

    // ---- K1: gemm1 || binA || detect (all independent) ----
    k_fused1<<<gb + G_BIN + 1, 256, 0, stream>>>(
        x, W1, as1, ad1, hbuf, als, ald, N, gb, in_sizes[0], in_sizes[2],
        src, dst, hist, E, EA, chunk,
        b1, in_sizes[5], W2, in_sizes[6], as2, in_sizes[7], ad2, in_sizes[8],
        b2, in_sizes[9], flags);
    // ---- CSR finish ----
    k_binC2<<<G_BIN, 256, 0, stream>>>(src, dst, hist, btot, ebuf, E, EA, chunk);
    k_binD<<<NBK, 256, 0, stream>>>(ebuf, btot, als, row_ptr, ecol, N);

    // ---- layer 1 gather + MFMA-fused layer-2 GEMM ----
    k_gat1g2<<<gatherb, 256, 0, stream>>>(row_ptr, ecol, ald, hbuf, h2buf,
                                          als2, ald2, b1, W2, as2, ad2,
                                          flags, N, npw);
    // ---- layer 2 gather -> output ----
    k_gather2<<<gatherb, 256, 0, stream>>>(row_ptr, ecol, als2, ald2, h2buf,
                                           d_out, b2, flags, N);
    (void)out_size; (void)ws_size; (void)n_in;
}